// Round 1
// baseline (353.868 us; speedup 1.0000x reference)
//
#include <hip/hip_runtime.h>
#include <stdint.h>

// ---------------------------------------------------------------------------
// HistoryEmbTable: emb.at[push_idx].set(x) then gather emb[pull_idx].
// Semantics must match numpy sequential assignment: for duplicate push
// indices, the LAST occurrence (highest i) wins.
//
// Strategy A (tag array, needs num_emb*4 bytes of ws):
//   tag[k] = 1 + argmax-winner push position (0 = never pushed), built with
//   atomicMax. Pull: out[j] = tag[k] ? x[tag[k]-1] : emb[k].
//
// Strategy B (fallback, open-addressed hash in whatever ws we have):
//   slot stores (key, winner+1); linear probing; same semantics.
// ---------------------------------------------------------------------------

__global__ void push_tag_kernel(const int* __restrict__ push_idx,
                                int* __restrict__ tag, int n) {
    int i = blockIdx.x * blockDim.x + threadIdx.x;
    if (i < n) {
        atomicMax(&tag[push_idx[i]], i + 1);
    }
}

__global__ void pull_tag_kernel(const int* __restrict__ pull_idx,
                                const int* __restrict__ tag,
                                const float* __restrict__ x,
                                const float* __restrict__ emb,
                                float* __restrict__ out, int n) {
    int j = blockIdx.x * blockDim.x + threadIdx.x;
    if (j < n) {
        int key = pull_idx[j];
        int t = tag[key];
        out[j] = t ? x[t - 1] : emb[key];
    }
}

// ---- hash fallback ----

__global__ void hash_insert_kernel(const int* __restrict__ push_idx,
                                   int* __restrict__ keys,
                                   int* __restrict__ vals,
                                   int n, unsigned cmask) {
    int i = blockIdx.x * blockDim.x + threadIdx.x;
    if (i >= n) return;
    int key = push_idx[i];
    unsigned slot = ((unsigned)key * 2654435761u) & cmask;
    for (;;) {
        int k = atomicCAS(&keys[slot], -1, key);
        if (k == -1 || k == key) {
            atomicMax(&vals[slot], i + 1);
            return;
        }
        slot = (slot + 1) & cmask;
    }
}

__global__ void hash_pull_kernel(const int* __restrict__ pull_idx,
                                 const int* __restrict__ keys,
                                 const int* __restrict__ vals,
                                 const float* __restrict__ x,
                                 const float* __restrict__ emb,
                                 float* __restrict__ out, int n, unsigned cmask) {
    int j = blockIdx.x * blockDim.x + threadIdx.x;
    if (j >= n) return;
    int key = pull_idx[j];
    unsigned slot = ((unsigned)key * 2654435761u) & cmask;
    for (;;) {
        int k = keys[slot];
        if (k == key) {
            int t = vals[slot];
            out[j] = t ? x[t - 1] : emb[key];
            return;
        }
        if (k == -1) {
            out[j] = emb[key];
            return;
        }
        slot = (slot + 1) & cmask;
    }
}

extern "C" void kernel_launch(void* const* d_in, const int* in_sizes, int n_in,
                              void* d_out, int out_size, void* d_ws, size_t ws_size,
                              hipStream_t stream) {
    const float* emb      = (const float*)d_in[0];
    const float* x        = (const float*)d_in[1];
    const int*   push_idx = (const int*)d_in[2];
    const int*   pull_idx = (const int*)d_in[3];
    float* out = (float*)d_out;

    const int num_emb = in_sizes[0];   // 60,000,000
    const int n       = in_sizes[2];   // 4,000,000 pushes
    const int n_pull  = in_sizes[3];   // 4,000,000 pulls

    const int B = 256;
    const int grid_push = (n + B - 1) / B;
    const int grid_pull = (n_pull + B - 1) / B;

    const size_t tag_bytes = (size_t)num_emb * sizeof(int);

    if (ws_size >= tag_bytes) {
        // Strategy A: full tag array.
        int* tag = (int*)d_ws;
        hipMemsetAsync(tag, 0, tag_bytes, stream);
        push_tag_kernel<<<grid_push, B, 0, stream>>>(push_idx, tag, n);
        pull_tag_kernel<<<grid_pull, B, 0, stream>>>(pull_idx, tag, x, emb, out, n_pull);
    } else {
        // Strategy B: open-addressed hash table in whatever ws we have.
        // Largest power-of-two C such that C * (4 keys + 4 vals) fits.
        size_t C = 1;
        while ((C << 1) * 8 <= ws_size) C <<= 1;
        unsigned cmask = (unsigned)(C - 1);
        int* keys = (int*)d_ws;
        int* vals = keys + C;
        hipMemsetAsync(keys, 0xFF, C * sizeof(int), stream);  // keys = -1
        hipMemsetAsync(vals, 0x00, C * sizeof(int), stream);  // vals = 0
        hash_insert_kernel<<<grid_push, B, 0, stream>>>(push_idx, keys, vals, n, cmask);
        hash_pull_kernel<<<grid_pull, B, 0, stream>>>(pull_idx, keys, vals, x, emb, out,
                                                      n_pull, cmask);
    }
}